// Round 8
// baseline (259.636 us; speedup 1.0000x reference)
//
#include <hip/hip_runtime.h>

#define NSTEP 2047
#define NB    4096

__device__ __forceinline__ float fexp2(float x) {
    float r; asm("v_exp_f32 %0, %1" : "=v"(r) : "v"(x)); return r;
}
__device__ __forceinline__ float frcp(float x) {
    float r; asm("v_rcp_f32 %0, %1" : "=v"(r) : "v"(x)); return r;
}
template <int CTRL>
__device__ __forceinline__ float qperm(float x) {
    int i = __builtin_bit_cast(int, x);
    i = __builtin_amdgcn_mov_dpp(i, CTRL, 0xF, 0xF, true);
    return __builtin_bit_cast(float, i);
}
#define XOR1 0xB1  // quad_perm [1,0,3,2]
#define XOR2 0x4E  // quad_perm [2,3,0,1]
#define ROT1 0x39  // quad_perm [1,2,3,0]
#define ROT3 0x93  // quad_perm [3,0,1,2]

__global__ __launch_bounds__(64, 1)
void cstr_kernel(const float* __restrict__ w, const float* __restrict__ Kp,
                 const float* __restrict__ Lp, const float* __restrict__ Mp,
                 const float* __restrict__ Mop, float* __restrict__ out)
{
    const int tid = blockIdx.x * 64 + threadIdx.x;   // 0..16383
    const int q   = tid & 3;                         // quad lane: owns rx[q]
    const int b   = tid >> 2;                        // sample

    constexpr float Hc  = 0.01f;
    constexpr float Acf = 1.0f - Hc;
    constexpr float Bcf = -0.5f * Hc * Hc;
    constexpr float T2L = 2.8853900817779268f;  // 2*log2(e)
    constexpr float L2E = 1.4426950408889634f;  // log2(e)
    constexpr float SC1 = 0.5f * Hc;
    constexpr float HH  = 0.5f * Hc;

    const float K0 = Kp[0], K1 = Kp[1], MoV = Mop[0];

    const float A00 = Lp[0], A11 = Lp[5], A22 = Lp[10], A33 = Lp[15];
    const float A01 = 0.5f * (Lp[1]  + Lp[4]);
    const float A02 = 0.5f * (Lp[2]  + Lp[8]);
    const float A03 = 0.5f * (Lp[3]  + Lp[12]);
    const float A12 = 0.5f * (Lp[6]  + Lp[9]);
    const float A13 = 0.5f * (Lp[7]  + Lp[13]);
    const float A23 = 0.5f * (Lp[11] + Lp[14]);

    const bool odd = (q & 1) != 0;
    const bool hi  = (q & 2) != 0;
    // per-lane constants (laundered into pinned VGPRs)
    float cTf  = odd ? -Hc : Hc;
    float cUf  = odd ? HH  : Hc;
    float c0f  = odd ? Bcf : 0.0f;
    float cKn  = (q == 2) ? K0 : (q == 3) ? K1 : 0.0f;
    float cwc  = (q == 1) ? Bcf : 0.0f;
    float am = (q == 0) ? Mp[0] : (q == 1) ? Mp[1] : (q == 2) ? Mp[2] : Mp[3];
    float a0 = (q == 0) ? A00 : (q == 1) ? A11 : (q == 2) ? A22 : A33;
    float a1 = (q == 0) ? A01 : (q == 1) ? A12 : (q == 2) ? A23 : A03;
    float a2 = (q == 0) ? A02 : (q == 1) ? A13 : (q == 2) ? A02 : A13;
    float a3 = (q == 0) ? A03 : (q == 1) ? A01 : (q == 2) ? A12 : A23;
    float shT2 = odd ? SC1 * T2L : 0.0f;   // tanh arg shift, pre-scaled by T2L
    float sB   = MoV * L2E;                // sigmoid bias (for exact resync)
    asm volatile("" : "+v"(cTf), "+v"(cUf), "+v"(c0f), "+v"(cKn), "+v"(cwc),
                      "+v"(am), "+v"(a0), "+v"(a1), "+v"(a2), "+v"(a3),
                      "+v"(shT2), "+v"(sB));

    const float* rw = w + (size_t)b * (2 * NSTEP) + (size_t)(q & 1) * NSTEP;
    // prologue loads (tail w's preloaded so the main loop needs no guards)
    const float w_0 = rw[0], w_1 = rw[1];
    const float we0 = rw[2042], we1 = rw[2043], we2 = rw[2044], we3 = rw[2045];
    const float w_T = rw[2046];

    const float th1 = 1.0f - 2.0f * frcp(fexp2(T2L) + 1.0f);        // tanh(1)
    const float thS = 1.0f - 2.0f * frcp(fexp2(SC1 * T2L) + 1.0f);  // tanh(H/2)

    // ---- t = 0 (delta=1, xhat0=(1,0), u0=K0) -> state entering step t=1 ----
    float St = (q == 0) ? (Acf + Hc * SC1 + Hc * K0 + w_0)
             : (q == 1) ? (Bcf - Hc * th1 + HH * K0 + w_0)
             : (q == 2) ? 1.0f : 0.0f;
    // TH = tanh(St + shift) for every lane (exact, prologue-only trans)
    float TH = 1.0f - 2.0f * frcp(fexp2(__builtin_fmaf(T2L, St, shT2)) + 1.0f);
    float U   = K0;
    float delta = 0.5f, PS = 0.0f;        // overwritten by first exact step
    float SXX = (q == 0) ? 1.0f : 0.0f;
    float SXY = 0.0f;
    float SD  = 1.0f;

    // One step. exact=true: recompute delta/TH via exp+rcp (resync).
    // exact=false: 2nd-order Taylor propagation (0 transcendentals).
    auto step = [&](float wi, bool acc, bool exact) {
        const float THP  = qperm<XOR1>(TH);          // partner tanh
        const float tb   = cTf * THP;
        const float base = __builtin_fmaf(Acf, St, tb);
        const float F    = __builtin_fmaf(cUf, U, base) + c0f;
        const float V    = hi ? F : St;              // rx component
        const float r1 = qperm<ROT1>(V);
        const float r2 = qperm<XOR2>(V);
        const float r3 = qperm<ROT3>(V);
        const float e1 = __builtin_fmaf(a0, V, am);
        const float e2 = a2 * r2;
        const float p1 = __builtin_fmaf(a1, r1, e1);
        const float p2 = __builtin_fmaf(a3, r3, e2);
        const float part = V * (p1 + p2);
        float ps = part + qperm<XOR1>(part);
        ps = ps + qperm<XOR2>(ps);                   // phi (sans Mo)
        if (exact) {
            const float E = fexp2(__builtin_fmaf(-L2E, ps, -sB));
            delta = frcp(E + 1.0f);                  // sigma(ps + Mo)
        } else {
            const float dphi = ps - PS;
            const float sd = __builtin_fmaf(-delta, delta, delta);  // d(1-d)
            const float cq = 0.5f - delta;
            const float qq = __builtin_fmaf(dphi, cq, 1.0f);
            const float rr = dphi * sd;
            delta = __builtin_fmaf(rr, qq, delta);
        }
        PS = ps;
        // u = K.F + delta*K.(X-F); reduces overlap the delta computation
        const float Dl = r2 - F;                     // lanes 2,3: x_partner - F
        const float tF = cKn * F;
        const float tD = cKn * Dl;
        float kF = tF + qperm<XOR1>(tF); kF = kF + qperm<XOR2>(kF);
        float kD = tD + qperm<XOR1>(tD); kD = kD + qperm<XOR2>(kD);
        const float un = __builtin_fmaf(delta, kD, kF);
        const float d  = delta * Dl;
        const float NH = F + d;
        if (acc) {
            SXX = __builtin_fmaf(V, V, SXX);
            SXY = __builtin_fmaf(V, r1, SXY);
            SD += delta;
        }
        const float cwv = wi + cwc;
        const float Xn  = __builtin_fmaf(cUf, un, base + cwv);
        const float Sn  = hi ? NH : Xn;
        if (exact) {
            const float tE = fexp2(__builtin_fmaf(T2L, Sn, shT2));
            TH = __builtin_fmaf(-2.0f, frcp(tE + 1.0f), 1.0f);
        } else {
            const float dS = Sn - St;
            const float s  = __builtin_fmaf(-TH, TH, 1.0f);  // sech^2
            const float pp = dS * s;
            const float q2 = __builtin_fmaf(-dS, TH, 1.0f);
            TH = __builtin_fmaf(pp, q2, TH);
        }
        St = Sn; U = un;
    };

    // t = 1 (exact; initializes delta/PS/TH chain)
    step(w_1, true, true);

    // t = 2 .. 2041: 255 iterations x 8 steps (1 exact + 7 Taylor each).
    float c0 = rw[2], c1 = rw[3], c2 = rw[4], c3 = rw[5];
    float c4 = rw[6], c5 = rw[7], c6 = rw[8], c7 = rw[9];
    for (int k = 0; k < 255; ++k) {
        const float* p = rw + ((k < 254) ? (10 + 8 * k) : 2);  // last: safe junk
        const float n0 = p[0], n1 = p[1], n2 = p[2], n3 = p[3];
        const float n4 = p[4], n5 = p[5], n6 = p[6], n7 = p[7];
        step(c0, true, true);
        step(c1, true, false); step(c2, true, false); step(c3, true, false);
        step(c4, true, false); step(c5, true, false); step(c6, true, false);
        step(c7, true, false);
        c0 = n0; c1 = n1; c2 = n2; c3 = n3;
        c4 = n4; c5 = n5; c6 = n6; c7 = n7;
    }

    // t = 2042 .. 2045 (exact + 3 Taylor), then t = 2046 (no accumulation)
    step(we0, true, true);
    step(we1, true, false); step(we2, true, false); step(we3, true, false);
    step(w_T, false, false);

    // epilogue: out = (Sx1^2+Sx2^2) + K-quadratic + SD + 10*|x_T|^2
    const float xx    = St * St;
    const float sxx_p = qperm<XOR1>(SXX);
    const float xx_s  = xx + qperm<XOR1>(xx);
    const float suu   = K0 * K0 * SXX + 2.0f * K0 * K1 * SXY + K1 * K1 * sxx_p;
    const float res   = (SXX + sxx_p) + suu + SD + 10.0f * xx_s;
    if (q == 0) out[b] = res;
}

extern "C" void kernel_launch(void* const* d_in, const int* in_sizes, int n_in,
                              void* d_out, int out_size, void* d_ws, size_t ws_size,
                              hipStream_t stream) {
    const float* w  = (const float*)d_in[0];
    const float* K  = (const float*)d_in[1];
    const float* L  = (const float*)d_in[2];
    const float* M  = (const float*)d_in[3];
    const float* Mo = (const float*)d_in[4];
    float* out = (float*)d_out;
    cstr_kernel<<<dim3(4 * NB / 64), dim3(64), 0, stream>>>(w, K, L, M, Mo, out);
}

// Round 9
// 134.772 us; speedup vs baseline: 1.9265x; 1.9265x over previous
//
#include <hip/hip_runtime.h>

#define NSTEP 2047

typedef float v4f __attribute__((ext_vector_type(4)));

__device__ __forceinline__ float fexp2(float x){float r;asm("v_exp_f32 %0, %1":"=v"(r):"v"(x));return r;}
__device__ __forceinline__ float frcp (float x){float r;asm("v_rcp_f32 %0, %1":"=v"(r):"v"(x));return r;}

__global__ __launch_bounds__(64, 1)
void cstr_kernel(const float* __restrict__ w, const float* __restrict__ Kp,
                 const float* __restrict__ Lp, const float* __restrict__ Mp,
                 const float* __restrict__ Mop, float* __restrict__ out)
{
    const int tid = blockIdx.x * 64 + threadIdx.x;   // 65536 threads
    const int c   = tid & 15;                        // time-chunk 0..15
    const int b   = tid >> 4;                        // sample 0..4095

    constexpr float Hc=0.01f, Acf=0.99f, Bcf=-0.5f*Hc*Hc;
    constexpr float T2L=2.8853900817779268f, L2E=1.4426950408889634f;
    constexpr float SC1=0.5f*Hc, SCT=SC1*T2L;

    const float K0=Kp[0], K1=Kp[1], MoV=Mop[0];
    // triangular quadratic form: phi = x1 g1 + x2 g2 + f1 g3 + f2 g4 + Mo
    const float c00=Lp[0], c11=Lp[5], c22=Lp[10], c33=Lp[15];
    const float c01=Lp[1]+Lp[4], c02=Lp[2]+Lp[8], c03=Lp[3]+Lp[12];
    const float c12=Lp[6]+Lp[9], c13=Lp[7]+Lp[13], c23=Lp[11]+Lp[14];
    const float m0=Mp[0], m1=Mp[1], m2=Mp[2], m3=Mp[3];
    const float sB = MoV * L2E;

    // chunk geometry: 896 iterations each; chunk c accumulates t in its window.
    // c<=6: exact start at t=1 (no seed error). c>=7: 768-step warm-up from 0-seed.
    const bool early = (c <= 6);
    const int  s  = early ? 1 : (c == 15 ? 1153 : 128*c - 767);   // t at i=0
    const int  iA = early ? 128*c : 768;                          // first acc iter
    const int  iB = early ? (128*c + 127) : (c == 15 ? 892 : 895);// last acc iter

    const float* rw0 = w + (size_t)b * (2*NSTEP);
    const float* rw1 = rw0 + NSTEP;

    const float w10 = rw0[0], w20 = rw1[0];
    const float th1 = 1.0f - 2.0f*frcp(fexp2(T2L) + 1.0f);       // tanh(1)

    // ---- state init ----
    float x1, x2, xh1, U;
    if (early) {
        x1 = Acf + Hc*SC1 + Hc*K0 + w10;
        x2 = Bcf - Hc*th1 + 0.5f*Hc*K0 + w20;
        xh1 = 1.0f; U = K0;
    } else { x1 = 0.0f; x2 = 0.0f; xh1 = 0.0f; U = 0.0f; }
    float xh2 = 0.0f;
    float THh1 = early ? th1 : 0.0f;                              // tanh(xh1)
    float THh2 = 1.0f - 2.0f*frcp(fexp2(SCT) + 1.0f);             // S(xh2=0)
    float THx1 = 1.0f - 2.0f*frcp(fexp2(T2L*x1) + 1.0f);          // tanh(x1)
    float THx2 = 1.0f - 2.0f*frcp(fexp2(__builtin_fmaf(T2L, x2, SCT)) + 1.0f); // S(x2)
    float delta = 0.5f, PS = 0.0f;
    float SXX1=0.0f, SXX2=0.0f, SXY=0.0f, SD=0.0f;

    auto step = [&](float w1v, float w2v, int icur, bool exact) {
        // F = f(xhat, U)
        const float hu = Hc*U;
        const float f1 = __builtin_fmaf(Acf, xh1, __builtin_fmaf(Hc, THh2, hu));
        const float f2 = __builtin_fmaf(Acf, xh2, __builtin_fmaf(-Hc, THh1,
                          __builtin_fmaf(0.5f, hu, Bcf)));
        // phi (sans Mo)
        float g1 = __builtin_fmaf(c00,x1,m0); g1=__builtin_fmaf(c01,x2,g1);
        g1=__builtin_fmaf(c02,f1,g1); g1=__builtin_fmaf(c03,f2,g1);
        float g2 = __builtin_fmaf(c11,x2,m1); g2=__builtin_fmaf(c12,f1,g2);
        g2=__builtin_fmaf(c13,f2,g2);
        float g3 = __builtin_fmaf(c22,f1,m2); g3=__builtin_fmaf(c23,f2,g3);
        float g4 = __builtin_fmaf(c33,f2,m3);
        const float ps = __builtin_fmaf(x1,g1, __builtin_fmaf(x2,g2,
                          __builtin_fmaf(f1,g3, f2*g4)));
        if (exact) {
            delta = frcp(1.0f + fexp2(__builtin_fmaf(-L2E, ps, -sB)));
        } else {  // 2nd-order sigmoid propagation
            const float dphi = ps - PS;
            const float sd = __builtin_fmaf(-delta, delta, delta);
            const float qq = __builtin_fmaf(dphi, 0.5f - delta, 1.0f);
            delta = __builtin_fmaf(dphi*sd, qq, delta);
        }
        PS = ps;
        // xhat, u
        const float d1 = x1 - f1, d2 = x2 - f2;
        const float nh1 = __builtin_fmaf(delta, d1, f1);
        const float nh2 = __builtin_fmaf(delta, d2, f2);
        const float un  = __builtin_fmaf(K1, nh2, K0*nh1);
        // masked accumulation (x before update)
        const float macc = (icur >= iA && icur <= iB) ? 1.0f : 0.0f;
        const float mx1 = macc*x1, mx2 = macc*x2;
        SXX1 = __builtin_fmaf(mx1, x1, SXX1);
        SXX2 = __builtin_fmaf(mx2, x2, SXX2);
        SXY  = __builtin_fmaf(mx1, x2, SXY);
        SD   = __builtin_fmaf(macc, delta, SD);
        // x update
        const float hun = Hc*un;
        const float nx1 = __builtin_fmaf(Acf, x1, __builtin_fmaf(Hc, THx2, w1v + hun));
        const float nx2 = __builtin_fmaf(Acf, x2, __builtin_fmaf(-Hc, THx1,
                           __builtin_fmaf(0.5f, hun, w2v + Bcf)));
        // tanh-state updates
        if (exact) {
            THh1 = __builtin_fmaf(-2.0f, frcp(fexp2(T2L*nh1)+1.0f), 1.0f);
            THh2 = __builtin_fmaf(-2.0f, frcp(fexp2(__builtin_fmaf(T2L,nh2,SCT))+1.0f), 1.0f);
            THx1 = __builtin_fmaf(-2.0f, frcp(fexp2(T2L*nx1)+1.0f), 1.0f);
            THx2 = __builtin_fmaf(-2.0f, frcp(fexp2(__builtin_fmaf(T2L,nx2,SCT))+1.0f), 1.0f);
        } else {  // 2nd-order tanh propagation (shift cancels in the difference)
            { const float dS=nh1-xh1, sc=__builtin_fmaf(-THh1,THh1,1.0f);
              THh1=__builtin_fmaf(dS*sc, __builtin_fmaf(-dS,THh1,1.0f), THh1); }
            { const float dS=nh2-xh2, sc=__builtin_fmaf(-THh2,THh2,1.0f);
              THh2=__builtin_fmaf(dS*sc, __builtin_fmaf(-dS,THh2,1.0f), THh2); }
            { const float dS=nx1-x1,  sc=__builtin_fmaf(-THx1,THx1,1.0f);
              THx1=__builtin_fmaf(dS*sc, __builtin_fmaf(-dS,THx1,1.0f), THx1); }
            { const float dS=nx2-x2,  sc=__builtin_fmaf(-THx2,THx2,1.0f);
              THx2=__builtin_fmaf(dS*sc, __builtin_fmaf(-dS,THx2,1.0f), THx2); }
        }
        x1=nx1; x2=nx2; xh1=nh1; xh2=nh2; U=un;
    };

    // ---- w streaming: 16B-aligned float4 rolling window (s-1 ≡ 0 mod 4) ----
    const float* q0 = rw0 + (s - 1);
    const float* q1 = rw1 + (s - 1);
    v4f Wa0 = *(const v4f*)(q0);     v4f Wb0 = *(const v4f*)(q1);
    v4f Wa1 = *(const v4f*)(q0 + 4); v4f Wb1 = *(const v4f*)(q1 + 4);
    v4f Wa2 = *(const v4f*)(q0 + 8); v4f Wb2 = *(const v4f*)(q1 + 8);

#define BLOCK8(ibase) \
    step(Wa0.y, Wb0.y, (ibase)+0, true ); \
    step(Wa0.z, Wb0.z, (ibase)+1, false); \
    step(Wa0.w, Wb0.w, (ibase)+2, false); \
    step(Wa1.x, Wb1.x, (ibase)+3, false); \
    step(Wa1.y, Wb1.y, (ibase)+4, false); \
    step(Wa1.z, Wb1.z, (ibase)+5, false); \
    step(Wa1.w, Wb1.w, (ibase)+6, false); \
    step(Wa2.x, Wb2.x, (ibase)+7, false);

    const float* qq0 = q0 + 12;
    const float* qq1 = q1 + 12;
    int ib = 0;
    for (int g = 0; g < 110; ++g) {   // blocks 0..109 with prefetch (max word 222: in-bounds all lanes)
        const v4f Na1 = *(const v4f*)(qq0);     const v4f Na2 = *(const v4f*)(qq0 + 4);
        const v4f Nb1 = *(const v4f*)(qq1);     const v4f Nb2 = *(const v4f*)(qq1 + 4);
        BLOCK8(ib);
        Wa0 = Wa2; Wa1 = Na1; Wa2 = Na2;
        Wb0 = Wb2; Wb1 = Nb1; Wb2 = Nb2;
        qq0 += 8; qq1 += 8; ib += 8;
    }
    // block 110 (i = 880..887): registers already hold words 220..222
    BLOCK8(880);

    // peeled final block (i = 888..895): scalar clamped loads (c=15 tail would
    // otherwise read past the last sample's row); snapshot x_T after i=893.
    float fa[8], fb[8];
#pragma unroll
    for (int j = 0; j < 8; ++j) {
        int t = s + 888 + j; int tc = (t > 2046) ? 2046 : t;
        fa[j] = rw0[tc]; fb[j] = rw1[tc];
    }
    step(fa[0], fb[0], 888, true );
    step(fa[1], fb[1], 889, false);
    step(fa[2], fb[2], 890, false);
    step(fa[3], fb[3], 891, false);
    step(fa[4], fb[4], 892, false);
    step(fa[5], fb[5], 893, false);
    const float xt1 = x1, xt2 = x2;   // x_T for c==15 (t=2046 done at i=893)
    step(fa[6], fb[6], 894, false);
    step(fa[7], fb[7], 895, false);

    // ---- per-chunk partial cost, then 16-lane reduction ----
    float P = SXX1 + SXX2 + SD;
    P = __builtin_fmaf(K0*K0, SXX1, P);
    P = __builtin_fmaf(2.0f*K0*K1, SXY, P);
    P = __builtin_fmaf(K1*K1, SXX2, P);
    if (c == 0)  P += 2.0f + K0*K0;                 // t=0 terms: x0.x0 + u0^2 + delta0
    if (c == 15) P += 10.0f * (xt1*xt1 + xt2*xt2);  // final cost
    P += __shfl_xor(P, 1);
    P += __shfl_xor(P, 2);
    P += __shfl_xor(P, 4);
    P += __shfl_xor(P, 8);
    if (c == 0) out[b] = P;
#undef BLOCK8
}

extern "C" void kernel_launch(void* const* d_in, const int* in_sizes, int n_in,
                              void* d_out, int out_size, void* d_ws, size_t ws_size,
                              hipStream_t stream) {
    const float* w  = (const float*)d_in[0];
    const float* K  = (const float*)d_in[1];
    const float* L  = (const float*)d_in[2];
    const float* M  = (const float*)d_in[3];
    const float* Mo = (const float*)d_in[4];
    float* out = (float*)d_out;
    cstr_kernel<<<dim3(1024), dim3(64), 0, stream>>>(w, K, L, M, Mo, out);
}

// Round 10
// 104.172 us; speedup vs baseline: 2.4924x; 1.2937x over previous
//
#include <hip/hip_runtime.h>

#define NSTEP 2047

typedef float v4f __attribute__((ext_vector_type(4), aligned(4)));

__device__ __forceinline__ float fexp2(float x){float r;asm("v_exp_f32 %0, %1":"=v"(r):"v"(x));return r;}
__device__ __forceinline__ float frcp (float x){float r;asm("v_rcp_f32 %0, %1":"=v"(r):"v"(x));return r;}

// Chunk geometry: 16 chunks, S=728 steps each, W=640 warm-up.
// chunk 0: exact from t=1, accumulates t=1..728.
// chunk c>=1: starts t=88c+1 (zero seed), warm 640, accumulates t=88c+641..88c+728.
// chunk 15: acc t=1961..2045, then t=2046 (no acc) -> x_T snapshot.
__global__ __launch_bounds__(64, 1)
void cstr_chunk(const float* __restrict__ w, const float* __restrict__ Kp,
                const float* __restrict__ Lp, const float* __restrict__ Mp,
                const float* __restrict__ Mop, float* __restrict__ ws)
{
    const int lane = threadIdx.x;
    const int wid  = blockIdx.x;          // 1024 waves
    const int c    = wid & 15;            // chunk (wave-uniform)
    const int b    = (wid >> 4) * 64 + lane;   // sample 0..4095

    constexpr float Hc=0.01f, Acf=0.99f, Bcf=-0.5f*Hc*Hc;
    constexpr float T2L=2.8853900817779268f, L2E=1.4426950408889634f;
    constexpr float SC1=0.5f*Hc, SCT=SC1*T2L;

    const float K0=Kp[0], K1=Kp[1], MoV=Mop[0];
    const float c00=Lp[0], c11=Lp[5], c22=Lp[10], c33=Lp[15];
    const float c01=Lp[1]+Lp[4], c02=Lp[2]+Lp[8], c03=Lp[3]+Lp[12];
    const float c12=Lp[6]+Lp[9], c13=Lp[7]+Lp[13], c23=Lp[11]+Lp[14];
    const float m0=Mp[0], m1=Mp[1], m2=Mp[2], m3=Mp[3];
    const float sB = MoV * L2E;

    const int t_s = (c == 0) ? 1 : 88 * c + 1;    // start t (== 1 mod 8 for all c)

    const float* rw0 = w + (size_t)b * (2*NSTEP);
    const float* rw1 = rw0 + NSTEP;

    const float w10 = rw0[0], w20 = rw1[0];
    const float th1 = 1.0f - 2.0f*frcp(fexp2(T2L) + 1.0f);   // tanh(1)

    // ---- state init ----
    float x1, x2, xh1, U, THh1;
    if (c == 0) {
        x1 = Acf + Hc*SC1 + Hc*K0 + w10;
        x2 = Bcf - Hc*th1 + 0.5f*Hc*K0 + w20;
        xh1 = 1.0f; U = K0; THh1 = th1;
    } else { x1 = 0.0f; x2 = 0.0f; xh1 = 0.0f; U = 0.0f; THh1 = 0.0f; }
    float xh2 = 0.0f;
    float THh2 = 1.0f - 2.0f*frcp(fexp2(SCT) + 1.0f);                       // S(xh2)
    float THx1 = 1.0f - 2.0f*frcp(fexp2(T2L*x1) + 1.0f);                    // tanh(x1)
    float THx2 = 1.0f - 2.0f*frcp(fexp2(__builtin_fmaf(T2L,x2,SCT)) + 1.0f);// S(x2)
    float delta = 0.5f, PS = 0.0f;
    float SXX1=0.0f, SXX2=0.0f, SXY=0.0f, SD=0.0f;

    auto step = [&](float w1v, float w2v, bool acc, bool exact) {
        const float hu = Hc*U;
        const float f1 = __builtin_fmaf(Acf, xh1, __builtin_fmaf(Hc, THh2, hu));
        const float f2 = __builtin_fmaf(Acf, xh2, __builtin_fmaf(-Hc, THh1,
                          __builtin_fmaf(0.5f, hu, Bcf)));
        float g1 = __builtin_fmaf(c00,x1,m0); g1=__builtin_fmaf(c01,x2,g1);
        g1=__builtin_fmaf(c02,f1,g1); g1=__builtin_fmaf(c03,f2,g1);
        float g2 = __builtin_fmaf(c11,x2,m1); g2=__builtin_fmaf(c12,f1,g2);
        g2=__builtin_fmaf(c13,f2,g2);
        float g3 = __builtin_fmaf(c22,f1,m2); g3=__builtin_fmaf(c23,f2,g3);
        float g4 = __builtin_fmaf(c33,f2,m3);
        const float ps = __builtin_fmaf(x1,g1, __builtin_fmaf(x2,g2,
                          __builtin_fmaf(f1,g3, f2*g4)));
        if (exact) {
            delta = frcp(1.0f + fexp2(__builtin_fmaf(-L2E, ps, -sB)));
        } else {
            const float dphi = ps - PS;
            const float sd = __builtin_fmaf(-delta, delta, delta);
            const float qq = __builtin_fmaf(dphi, 0.5f - delta, 1.0f);
            delta = __builtin_fmaf(dphi*sd, qq, delta);
        }
        PS = ps;
        const float d1 = x1 - f1, d2 = x2 - f2;
        const float nh1 = __builtin_fmaf(delta, d1, f1);
        const float nh2 = __builtin_fmaf(delta, d2, f2);
        const float un  = __builtin_fmaf(K1, nh2, K0*nh1);
        if (acc) {   // x BEFORE update; call sites pass literals -> no masks
            SXX1 = __builtin_fmaf(x1, x1, SXX1);
            SXX2 = __builtin_fmaf(x2, x2, SXX2);
            SXY  = __builtin_fmaf(x1, x2, SXY);
            SD  += delta;
        }
        const float hun = Hc*un;
        const float nx1 = __builtin_fmaf(Acf, x1, __builtin_fmaf(Hc, THx2, w1v + hun));
        const float nx2 = __builtin_fmaf(Acf, x2, __builtin_fmaf(-Hc, THx1,
                           __builtin_fmaf(0.5f, hun, w2v + Bcf)));
        if (exact) {
            THh1 = __builtin_fmaf(-2.0f, frcp(fexp2(T2L*nh1)+1.0f), 1.0f);
            THh2 = __builtin_fmaf(-2.0f, frcp(fexp2(__builtin_fmaf(T2L,nh2,SCT))+1.0f), 1.0f);
            THx1 = __builtin_fmaf(-2.0f, frcp(fexp2(T2L*nx1)+1.0f), 1.0f);
            THx2 = __builtin_fmaf(-2.0f, frcp(fexp2(__builtin_fmaf(T2L,nx2,SCT))+1.0f), 1.0f);
        } else {
            { const float dS=nh1-xh1, sc=__builtin_fmaf(-THh1,THh1,1.0f);
              THh1=__builtin_fmaf(dS*sc, __builtin_fmaf(-dS,THh1,1.0f), THh1); }
            { const float dS=nh2-xh2, sc=__builtin_fmaf(-THh2,THh2,1.0f);
              THh2=__builtin_fmaf(dS*sc, __builtin_fmaf(-dS,THh2,1.0f), THh2); }
            { const float dS=nx1-x1,  sc=__builtin_fmaf(-THx1,THx1,1.0f);
              THx1=__builtin_fmaf(dS*sc, __builtin_fmaf(-dS,THx1,1.0f), THx1); }
            { const float dS=nx2-x2,  sc=__builtin_fmaf(-THx2,THx2,1.0f);
              THx2=__builtin_fmaf(dS*sc, __builtin_fmaf(-dS,THx2,1.0f), THx2); }
        }
        x1=nx1; x2=nx2; xh1=nh1; xh2=nh2; U=un;
    };

    // ---- rolling 16B-aligned w stream (t_s-1 == 0 mod 8) ----
    const float* q0 = rw0 + (t_s - 1);
    const float* q1 = rw1 + (t_s - 1);
    v4f Wa0 = *(const v4f*)(q0);     v4f Wb0 = *(const v4f*)(q1);
    v4f Wa1 = *(const v4f*)(q0 + 4); v4f Wb1 = *(const v4f*)(q1 + 4);
    v4f Wa2 = *(const v4f*)(q0 + 8); v4f Wb2 = *(const v4f*)(q1 + 8);
    const float* p0 = q0 + 12;
    const float* p1 = q1 + 12;

    auto runblk = [&](bool ACC) {   // one 8-step block with next-block prefetch
        const v4f Na1 = *(const v4f*)(p0); const v4f Na2 = *(const v4f*)(p0 + 4);
        const v4f Nb1 = *(const v4f*)(p1); const v4f Nb2 = *(const v4f*)(p1 + 4);
        step(Wa0.y, Wb0.y, ACC, true );
        step(Wa0.z, Wb0.z, ACC, false);
        step(Wa0.w, Wb0.w, ACC, false);
        step(Wa1.x, Wb1.x, ACC, false);
        step(Wa1.y, Wb1.y, ACC, false);
        step(Wa1.z, Wb1.z, ACC, false);
        step(Wa1.w, Wb1.w, ACC, false);
        step(Wa2.x, Wb2.x, ACC, false);
        Wa0 = Wa2; Wa1 = Na1; Wa2 = Na2;
        Wb0 = Wb2; Wb1 = Nb1; Wb2 = Nb2;
        p0 += 8; p1 += 8;
    };

    // main blocks 0..88 (with prefetch); phase split is wave-uniform
    if (c == 0) {
        for (int g = 0; g < 89; ++g) runblk(true);
    } else {
        for (int g = 0; g < 80; ++g) runblk(false);   // warm-up, no acc
        for (int g = 80; g < 89; ++g) runblk(true);   // window
    }
    // block 89 (i = 712..719): registers already hold words 712..723
    step(Wa0.y, Wb0.y, true, true );
    step(Wa0.z, Wb0.z, true, false);
    step(Wa0.w, Wb0.w, true, false);
    step(Wa1.x, Wb1.x, true, false);
    step(Wa1.y, Wb1.y, true, false);
    step(Wa1.z, Wb1.z, true, false);
    step(Wa1.w, Wb1.w, true, false);
    step(Wa2.x, Wb2.x, true, false);

    // peeled block (i = 720..727): clamped scalar loads (chunk 15 tail OOB guard)
    float fa[8], fb[8];
#pragma unroll
    for (int j = 0; j < 8; ++j) {
        int t = t_s + 720 + j; int tc = (t > 2046) ? 2046 : t;
        fa[j] = rw0[tc]; fb[j] = rw1[tc];
    }
    const bool late = (c == 15);
    step(fa[0], fb[0], true,  true );
    step(fa[1], fb[1], true,  false);
    step(fa[2], fb[2], true,  false);
    step(fa[3], fb[3], true,  false);
    step(fa[4], fb[4], true,  false);
    step(fa[5], fb[5], !late, false);      // chunk15: t=2046, no acc
    const float xt1 = x1, xt2 = x2;        // chunk15: x_T = x_2047
    step(fa[6], fb[6], !late, false);
    step(fa[7], fb[7], !late, false);

    // per-chunk partial cost -> ws[c][b]
    float P = SXX1 + SXX2 + SD;
    P = __builtin_fmaf(K0*K0, SXX1, P);
    P = __builtin_fmaf(2.0f*K0*K1, SXY, P);
    P = __builtin_fmaf(K1*K1, SXX2, P);
    if (c == 0)  P += 2.0f + K0*K0;                 // t=0 terms
    if (late)    P += 10.0f * (xt1*xt1 + xt2*xt2);  // final cost
    ws[c * 4096 + b] = P;
}

__global__ __launch_bounds__(64)
void cstr_reduce(const float* __restrict__ ws, float* __restrict__ out)
{
    const int b = blockIdx.x * 64 + threadIdx.x;   // 0..4095
    float s = 0.0f;
#pragma unroll
    for (int c = 0; c < 16; ++c) s += ws[c * 4096 + b];
    out[b] = s;
}

extern "C" void kernel_launch(void* const* d_in, const int* in_sizes, int n_in,
                              void* d_out, int out_size, void* d_ws, size_t ws_size,
                              hipStream_t stream) {
    const float* w  = (const float*)d_in[0];
    const float* K  = (const float*)d_in[1];
    const float* L  = (const float*)d_in[2];
    const float* M  = (const float*)d_in[3];
    const float* Mo = (const float*)d_in[4];
    float* out = (float*)d_out;
    float* ws  = (float*)d_ws;                     // 16*4096*4 B = 256 KB
    cstr_chunk <<<dim3(1024), dim3(64), 0, stream>>>(w, K, L, M, Mo, ws);
    cstr_reduce<<<dim3(64),   dim3(64), 0, stream>>>(ws, out);
}